// Round 9
// baseline (97934.741 us; speedup 1.0000x reference)
//
#include <hip/hip_runtime.h>
#include <hip/hip_cooperative_groups.h>

namespace cg = cooperative_groups;

#define B_ 128
#define T_ 1500
#define L_ 300
#define V_ 1000
#define H_ 128
#define CHUNK 375

// ---- workspace BYTE offsets ----
#define OB_EBUF  0ull          // f32 128*1500
#define OB_PBUF  768000ull     // f32 128*1500
#define OB_PMX   1536000ull    // f32 128*4
#define OB_PSUM  1538048ull    // f64 128*4  (8B aligned)
#define OB_H     1542144ull    // f32 128*128
#define OB_C     1607680ull    // f32 128*128
#define OB_CTX   1673216ull    // f32 128*128
#define OB_QC    1738752ull    // f32 300*128*256 = 39321600 B

// fp32 sigmoid with reference rounding points: e=round_f32(exp(-x)); 1/(1+e) in f32
__device__ __forceinline__ float sigq(float x) {
    float e = (float)exp(-(double)x);
    return __fdiv_rn(1.0f, __fadd_rn(1.0f, e));
}
__device__ __forceinline__ float tanhq(float x) { return (float)tanh((double)x); }

// K3: serial recurrence shadowing the numpy fp32 trajectory.
// 512 blocks x 256 threads cooperative; 4 grid syncs per step.
__global__ __launch_bounds__(256) void decoder_coop(
    const float* __restrict__ key, const float* __restrict__ value,
    const int* __restrict__ enc_len, const int* __restrict__ y,
    const float* __restrict__ emb, const float* __restrict__ W_ih,
    const float* __restrict__ W_hh, const float* __restrict__ b_ih,
    const float* __restrict__ b_hh,
    float* __restrict__ e_buf, float* __restrict__ p_buf,
    float* __restrict__ pmx, double* __restrict__ psum,
    float* __restrict__ h_g, float* __restrict__ c_g, float* __restrict__ ctx_g,
    float* __restrict__ qc, float* __restrict__ out_attn) {
    cg::grid_group grid = cg::this_grid();
    const int bid = blockIdx.x, tid = threadIdx.x;

    __shared__ float sx[256], sctx[128], shh[128], sg[512];
    __shared__ float smax[4];
    __shared__ double sred[4];
    __shared__ float sattn[256];

    for (int l = 0; l <= L_; ++l) {
        // ---------- PHASE 1 (blocks 0..127): qc store + LSTM step ----------
        if (bid < B_) {
            const int b = bid;
            if (l > 0) {
                qc[((size_t)(l - 1) * B_ + b) * 256 + tid] =
                    (tid < 128) ? h_g[b * 128 + tid] : ctx_g[b * 128 + (tid - 128)];
            }
            if (l < L_) {
                if (l == 0) {
                    sx[tid] = 0.0f;
                    if (tid < 128) {
                        sctx[tid] = value[(size_t)b * T_ * H_ + tid];  // value[b,0,:]
                        shh[tid] = 0.0f;
                    }
                } else {
                    int yv = y[b * L_ + (l - 1)];
                    sx[tid] = emb[(size_t)yv * 256 + tid];
                    if (tid < 128) {
                        sctx[tid] = ctx_g[b * 128 + tid];
                        shh[tid] = h_g[b * 128 + tid];
                    }
                }
                __syncthreads();
                // gates: ((inp@W_ih.T + b_ih) + h@W_hh.T) + b_hh, serial fp32 FMA chains
#pragma unroll
                for (int jj = 0; jj < 2; ++jj) {
                    int j = tid + jj * 256;
                    const float* wr = W_ih + (size_t)j * 384;
                    float acc = 0.0f;
                    for (int k = 0; k < 256; ++k) acc = __fmaf_rn(sx[k], wr[k], acc);
                    for (int k = 0; k < 128; ++k) acc = __fmaf_rn(sctx[k], wr[256 + k], acc);
                    float t2 = __fadd_rn(acc, b_ih[j]);
                    const float* wh = W_hh + (size_t)j * 128;
                    float hacc = 0.0f;
                    for (int k = 0; k < 128; ++k) hacc = __fmaf_rn(shh[k], wh[k], hacc);
                    float t4 = __fadd_rn(t2, hacc);
                    sg[j] = __fadd_rn(t4, b_hh[j]);
                }
                __syncthreads();
                if (tid < 128) {
                    float ig = sigq(sg[tid]);
                    float fg = sigq(sg[128 + tid]);
                    float gt = tanhq(sg[256 + tid]);
                    float og = sigq(sg[384 + tid]);
                    float cold = (l == 0) ? 0.0f : c_g[b * 128 + tid];
                    float cn = __fadd_rn(__fmul_rn(fg, cold), __fmul_rn(ig, gt));
                    float hn = __fmul_rn(og, tanhq(cn));
                    c_g[b * 128 + tid] = cn;
                    h_g[b * 128 + tid] = hn;
                }
            }
        }
        if (l == L_) break;
        grid.sync();

        // ---------- PHASE 2 (all 512): energies, serial fp32 FMA over d ----------
        {
            const int b = bid >> 2, ch = bid & 3, t0 = ch * CHUNK;
            const int el = enc_len[b];
            if (tid < 128) shh[tid] = h_g[b * 128 + tid];
            __syncthreads();
            float lm = -3.4e38f;
            for (int trel = tid; trel < CHUNK; trel += 256) {
                int t = t0 + trel;
                const float* kr = key + ((size_t)b * T_ + t) * H_;
                float acc = 0.0f;
                for (int d = 0; d < 128; ++d) acc = __fmaf_rn(kr[d], shh[d], acc);
                if (t >= el) acc = -1.0e9f;
                e_buf[(size_t)b * T_ + t] = acc;
                lm = fmaxf(lm, acc);
            }
#pragma unroll
            for (int off = 32; off >= 1; off >>= 1) lm = fmaxf(lm, __shfl_xor(lm, off));
            if ((tid & 63) == 0) smax[tid >> 6] = lm;
            __syncthreads();
            if (tid == 0)
                pmx[b * 4 + ch] = fmaxf(fmaxf(smax[0], smax[1]), fmaxf(smax[2], smax[3]));
        }
        grid.sync();

        // ---------- PHASE 3 (all 512): p = round_f32(exp(e - M_global)), partial sums ----------
        {
            const int b = bid >> 2, ch = bid & 3, t0 = ch * CHUNK;
            float M = fmaxf(fmaxf(pmx[b * 4 + 0], pmx[b * 4 + 1]),
                            fmaxf(pmx[b * 4 + 2], pmx[b * 4 + 3]));
            double sum = 0.0;
            for (int trel = tid; trel < CHUNK; trel += 256) {
                int t = t0 + trel;
                float arg = __fsub_rn(e_buf[(size_t)b * T_ + t], M);
                float p = (float)exp((double)arg);
                p_buf[(size_t)b * T_ + t] = p;
                sum += (double)p;
            }
#pragma unroll
            for (int off = 32; off >= 1; off >>= 1) sum += __shfl_xor(sum, off);
            if ((tid & 63) == 0) sred[tid >> 6] = sum;
            __syncthreads();
            if (tid == 0) psum[b * 4 + ch] = sred[0] + sred[1] + sred[2] + sred[3];
        }
        grid.sync();

        // ---------- PHASE 4 (blocks 0..127): attn = p/S (f32), ctx serial over t ----------
        if (bid < B_) {
            const int b = bid;
            float S = (float)(psum[b * 4 + 0] + psum[b * 4 + 1] +
                              psum[b * 4 + 2] + psum[b * 4 + 3]);
            float acc = 0.0f;  // ctx[d] accumulator, d = tid (<128)
            for (int tt0 = 0; tt0 < T_; tt0 += 256) {
                int t = tt0 + tid;
                float a = 0.0f;
                if (t < T_) {
                    a = __fdiv_rn(p_buf[(size_t)b * T_ + t], S);
                    if (b == 0) out_attn[(size_t)l * T_ + t] = a;
                }
                sattn[tid] = a;
                __syncthreads();
                if (tid < 128) {
                    int lim = min(256, T_ - tt0);
                    for (int tt = 0; tt < lim; ++tt)
                        acc = __fmaf_rn(sattn[tt],
                                        value[((size_t)b * T_ + tt0 + tt) * H_ + tid], acc);
                }
                __syncthreads();
            }
            if (tid < 128) ctx_g[b * 128 + tid] = acc;
        }
        grid.sync();
    }
}

// K4: logits GEMM (38400 x 1000, K=256), fp32 (non-amplified output path)
__global__ __launch_bounds__(256) void logits_gemm(const float* __restrict__ qc,
                                                   const float* __restrict__ emb,
                                                   const float* __restrict__ b_out,
                                                   float* __restrict__ out) {
    __shared__ float As[64][33];
    __shared__ float Bs[128][33];
    const int rowBase = blockIdx.x * 64;
    const int v0 = blockIdx.y * 128;
    const int tid = threadIdx.x;
    const int tx = tid & 15, ty = tid >> 4;
    float acc[4][8];
#pragma unroll
    for (int i = 0; i < 4; ++i)
#pragma unroll
        for (int j = 0; j < 8; ++j) acc[i][j] = 0.f;

    for (int k0 = 0; k0 < 256; k0 += 32) {
#pragma unroll
        for (int f = tid; f < 512; f += 256) {
            int m = f >> 3, kq = f & 7;
            float4 v = *(const float4*)&qc[(size_t)(rowBase + m) * 256 + k0 + kq * 4];
            As[m][kq * 4 + 0] = v.x; As[m][kq * 4 + 1] = v.y;
            As[m][kq * 4 + 2] = v.z; As[m][kq * 4 + 3] = v.w;
        }
#pragma unroll
        for (int f = tid; f < 1024; f += 256) {
            int n = f >> 3, kq = f & 7;
            int v = v0 + n;
            float4 vv = (v < V_) ? *(const float4*)&emb[(size_t)v * 256 + k0 + kq * 4]
                                 : make_float4(0.f, 0.f, 0.f, 0.f);
            Bs[n][kq * 4 + 0] = vv.x; Bs[n][kq * 4 + 1] = vv.y;
            Bs[n][kq * 4 + 2] = vv.z; Bs[n][kq * 4 + 3] = vv.w;
        }
        __syncthreads();
#pragma unroll 4
        for (int k = 0; k < 32; ++k) {
            float a[4], bb[8];
#pragma unroll
            for (int i = 0; i < 4; ++i) a[i] = As[ty * 4 + i][k];
#pragma unroll
            for (int j = 0; j < 8; ++j) bb[j] = Bs[tx * 8 + j][k];
#pragma unroll
            for (int i = 0; i < 4; ++i)
#pragma unroll
                for (int j = 0; j < 8; ++j) acc[i][j] += a[i] * bb[j];
        }
        __syncthreads();
    }
#pragma unroll
    for (int i = 0; i < 4; ++i) {
        int r = rowBase + ty * 4 + i;
        int li = r >> 7, bi = r & 127;
        size_t base = (size_t)bi * (L_ * V_) + (size_t)li * V_;
#pragma unroll
        for (int j = 0; j < 8; ++j) {
            int v = v0 + tx * 8 + j;
            if (v < V_) out[base + v] = acc[i][j] + b_out[v];
        }
    }
}

extern "C" void kernel_launch(void* const* d_in, const int* in_sizes, int n_in,
                              void* d_out, int out_size, void* d_ws, size_t ws_size,
                              hipStream_t stream) {
    const float* key   = (const float*)d_in[0];
    const float* value = (const float*)d_in[1];
    const int*   encl  = (const int*)d_in[2];
    const int*   y     = (const int*)d_in[3];
    const float* emb   = (const float*)d_in[4];
    const float* W_ih  = (const float*)d_in[5];
    const float* W_hh  = (const float*)d_in[6];
    const float* b_ih  = (const float*)d_in[7];
    const float* b_hh  = (const float*)d_in[8];
    const float* b_out = (const float*)d_in[9];
    float* out = (float*)d_out;
    char* wsb = (char*)d_ws;

    float*  e_buf = (float*)(wsb + OB_EBUF);
    float*  p_buf = (float*)(wsb + OB_PBUF);
    float*  pmx   = (float*)(wsb + OB_PMX);
    double* psum  = (double*)(wsb + OB_PSUM);
    float*  h_g   = (float*)(wsb + OB_H);
    float*  c_g   = (float*)(wsb + OB_C);
    float*  ctx_g = (float*)(wsb + OB_CTX);
    float*  qc    = (float*)(wsb + OB_QC);
    float*  out_attn = out + (size_t)B_ * L_ * V_;

    void* args[] = {(void*)&key, (void*)&value, (void*)&encl, (void*)&y,
                    (void*)&emb, (void*)&W_ih, (void*)&W_hh, (void*)&b_ih, (void*)&b_hh,
                    (void*)&e_buf, (void*)&p_buf, (void*)&pmx, (void*)&psum,
                    (void*)&h_g, (void*)&c_g, (void*)&ctx_g, (void*)&qc, (void*)&out_attn};
    hipLaunchCooperativeKernel((const void*)decoder_coop, dim3(512), dim3(256), args, 0, stream);

    logits_gemm<<<dim3(600, 8), 256, 0, stream>>>(qc, emb, b_out, out);
}